// Round 9
// baseline (300.450 us; speedup 1.0000x reference)
//
#include <hip/hip_runtime.h>

typedef unsigned int u32;
typedef unsigned long long u64;

#define NB 10
#define BLOCKS 2048       // 8 blocks/CU -> 32 waves/CU in the nt regime
#define TPB 256           // 4 waves
#define ITERS 16          // float4 batches per thread
#define DEPTH 4           // register pipeline depth (batches in flight)
#define WAVE_F4 (ITERS * 64)   // 1024 contiguous float4 per wave

// ws layout: bin b owns cache line at u32 index 32*b:
//   [32b+0..1] u64 sum(ffx), [32b+2] count, [32b+3] positives
__global__ void rd_zero_ws(u32* __restrict__ ws) {
    if (threadIdx.x < 320) ws[threadIdx.x] = 0u;
}

// Non-temporal 16 B loads via 4 scalar nt dword loads (clang merges adjacent
// nt loads into global_load_dwordx4 nt). Streamed data gets no cache alloc.
__device__ __forceinline__ int4 nt_load_i4(const int4* p) {
    const int* q = (const int*)p;
    int4 r;
    r.x = __builtin_nontemporal_load(q);
    r.y = __builtin_nontemporal_load(q + 1);
    r.z = __builtin_nontemporal_load(q + 2);
    r.w = __builtin_nontemporal_load(q + 3);
    return r;
}

__device__ __forceinline__ float4 nt_load_f4(const float4* p) {
    const float* q = (const float*)p;
    float4 r;
    r.x = __builtin_nontemporal_load(q);
    r.y = __builtin_nontemporal_load(q + 1);
    r.z = __builtin_nontemporal_load(q + 2);
    r.w = __builtin_nontemporal_load(q + 3);
    return r;
}

// Per element: sigmoid -> bin -> 4 packed u64 register accumulators.
// 6-bit count/pos fields; 12-bit conf-frac fields (7-bit fixed point),
// unpack window 32 elems: 32*127 = 4064 < 4095 (field-safe).
__device__ __forceinline__ void rd_acc(float x, int lab,
                                       u64& c64, u64& p64, u64& flo, u64& fhi) {
    float e = __expf(-x);
    float conf = __builtin_amdgcn_rcpf(1.0f + e);        // sigmoid
    float t10 = __builtin_fmaf(conf, 10.0f, -1e-6f);     // bins are (l,u]
    int b = min(9, (int)t10);
    float frac = t10 - (float)b;                         // [0,1)
    u32 ffx = (u32)__builtin_fmaf(frac, 127.0f, 0.5f);   // 7-bit fixed point

    u32 sh6 = (u32)(b * 6);
    c64 += 1ull << sh6;                                  // 6-bit count fields
    p64 += ((u64)(u32)lab) << sh6;                       // 6-bit positive fields

    bool lo = b < 5;
    u32 sh12 = (u32)(b * 12);
    u32 shf = lo ? sh12 : (sh12 - 60u);
    u64 v = ((u64)ffx) << shf;                           // 12-bit fields, 5 per u64
    flo += lo ? v : 0ull;
    fhi += lo ? 0ull : v;
}

__device__ __forceinline__ void rd_acc4(const float4& x, const int4& y,
                                        u64& c64, u64& p64, u64& flo, u64& fhi) {
    rd_acc(x.x, y.x, c64, p64, flo, fhi);
    rd_acc(x.y, y.y, c64, p64, flo, fhi);
    rd_acc(x.z, y.z, c64, p64, flo, fhi);
    rd_acc(x.w, y.w, c64, p64, flo, fhi);
}

// r8 (full-nt: rd_hist < 78 us) with ONE change: 2x blocks (8/CU -> 32
// waves/CU), half ITERS. In the nt regime every load pays full HBM latency
// (no L2/L3 hits), so latency-hiding capacity (waves x outstanding loads)
// may now be the binding constraint — it was only ever tested in the
// allocation-throttled regime where it was provably irrelevant.
__global__ __launch_bounds__(TPB, 4) void rd_hist(const float* __restrict__ logits,
                                                  const int* __restrict__ labels,
                                                  u32* __restrict__ ws,
                                                  long long n) {
    u32 cp[NB], cf[NB];
    #pragma unroll
    for (int b = 0; b < NB; ++b) { cp[b] = 0u; cf[b] = 0u; }

    const float4* l4 = (const float4*)logits;
    const int4*   i4 = (const int4*)labels;
    int lane = threadIdx.x & 63;
    int wave = threadIdx.x >> 6;
    long long nf4 = n >> 2;
    long long seg = (long long)blockIdx.x * (4 * WAVE_F4);

    u64 c64 = 0, p64 = 0, flo = 0, fhi = 0;

    #define UNPACK() do {                                                   \
        _Pragma("unroll")                                                   \
        for (int b = 0; b < NB; ++b) {                                      \
            u32 cnt = (u32)(c64 >> (6 * b)) & 63u;                          \
            u32 pos = (u32)(p64 >> (6 * b)) & 63u;                          \
            cp[b] += cnt | (pos << 16);                                     \
            cf[b] += (b < 5) ? ((u32)(flo >> (12 * b)) & 4095u)             \
                             : ((u32)(fhi >> (12 * (b - 5))) & 4095u);      \
        }                                                                   \
        c64 = 0; p64 = 0; flo = 0; fhi = 0;                                 \
    } while (0)

    if (seg + 4 * WAVE_F4 <= nf4) {
        long long gb = seg + (long long)wave * WAVE_F4;
        const float4* gl = l4 + gb + lane;
        const int4*   gi = i4 + gb + lane;

        // prologue: fill the ring (4 batches = 8 independent 16 B loads)
        float4 px0 = nt_load_f4(gl + 0 * 64);
        float4 px1 = nt_load_f4(gl + 1 * 64);
        float4 px2 = nt_load_f4(gl + 2 * 64);
        float4 px3 = nt_load_f4(gl + 3 * 64);
        int4 py0 = nt_load_i4(gi + 0 * 64);
        int4 py1 = nt_load_i4(gi + 1 * 64);
        int4 py2 = nt_load_i4(gi + 2 * 64);
        int4 py3 = nt_load_i4(gi + 3 * 64);

        #pragma unroll
        for (int t = 0; t < ITERS; ++t) {
            const int s = t & 3;            // static after unroll
            float4 x; int4 y;
            if      (s == 0) { x = px0; y = py0; }
            else if (s == 1) { x = px1; y = py1; }
            else if (s == 2) { x = px2; y = py2; }
            else             { x = px3; y = py3; }
            if (t + DEPTH < ITERS) {        // refill freed slot BEFORE compute
                if      (s == 0) { px0 = nt_load_f4(gl + (t + DEPTH) * 64);
                                   py0 = nt_load_i4(gi + (t + DEPTH) * 64); }
                else if (s == 1) { px1 = nt_load_f4(gl + (t + DEPTH) * 64);
                                   py1 = nt_load_i4(gi + (t + DEPTH) * 64); }
                else if (s == 2) { px2 = nt_load_f4(gl + (t + DEPTH) * 64);
                                   py2 = nt_load_i4(gi + (t + DEPTH) * 64); }
                else             { px3 = nt_load_f4(gl + (t + DEPTH) * 64);
                                   py3 = nt_load_i4(gi + (t + DEPTH) * 64); }
            }
            rd_acc4(x, y, c64, p64, flo, fhi);
            if ((t & 7) == 7) UNPACK();     // every 32 elems, field-safe
        }
    }

    // generic tail (empty at N=2^25: 2048*4096 f4 covers exactly)
    long long done_f4 = ((long long)gridDim.x < nf4 / (4 * WAVE_F4)
                             ? (long long)gridDim.x
                             : nf4 / (4 * WAVE_F4)) * (4 * WAVE_F4);
    long long tail = done_f4 * 4;
    if (tail < n) {
        long long tid    = (long long)blockIdx.x * blockDim.x + threadIdx.x;
        long long stride = (long long)gridDim.x * blockDim.x;
        for (long long i = tail + tid; i < n; i += stride) {
            float e = __expf(-logits[i]);
            float conf = __builtin_amdgcn_rcpf(1.0f + e);
            float t10 = __builtin_fmaf(conf, 10.0f, -1e-6f);
            int b = min(9, (int)t10);
            float frac = t10 - (float)b;
            u32 ffx = (u32)__builtin_fmaf(frac, 127.0f, 0.5f);
            atomicAdd((u64*)&ws[32 * b], (u64)ffx);
            atomicAdd(&ws[32 * b + 2], 1u);
            atomicAdd(&ws[32 * b + 3], (u32)labels[i]);
        }
    }
    #undef UNPACK

    // wave reduce + block combine (LDS: 320 B total)
    __shared__ u32 s_cp[4][NB];
    __shared__ u32 s_cf[4][NB];
    #pragma unroll
    for (int b = 0; b < NB; ++b) {
        u32 c = cp[b];                  // per-thread count <= 64 -> 16-bit safe
        u32 f = cf[b];
        #pragma unroll
        for (int off = 32; off; off >>= 1) {
            c += __shfl_down(c, off, 64);
            f += __shfl_down(f, off, 64);
        }
        if (lane == 0) { s_cp[wave][b] = c; s_cf[wave][b] = f; }
    }
    __syncthreads();

    if (threadIdx.x < NB) {
        int b = threadIdx.x;
        u32 c = s_cp[0][b] + s_cp[1][b] + s_cp[2][b] + s_cp[3][b];
        u64 f = (u64)s_cf[0][b] + s_cf[1][b] + s_cf[2][b] + s_cf[3][b];
        atomicAdd((u64*)&ws[32 * b], f);
        atomicAdd(&ws[32 * b + 2], c & 0xFFFFu);
        atomicAdd(&ws[32 * b + 3], c >> 16);
    }
}

__global__ void rd_finalize(const u32* __restrict__ ws, float* __restrict__ out) {
    int b = threadIdx.x;
    if (b < NB) {
        u64 f   = *(const u64*)&ws[32 * b];
        u32 cnt = ws[32 * b + 2];
        u32 pos = ws[32 * b + 3];
        double sumconf = ((double)b * (double)cnt + (double)f * (1.0 / 127.0)) * 0.1;
        float denom = fmaxf((float)cnt, 1.0f);
        bool ne = cnt > 0u;
        out[b]      = ne ? ((float)pos / denom) : 0.0f;
        out[NB + b] = ne ? (float)(sumconf / (double)denom) : 0.0f;
    }
}

extern "C" void kernel_launch(void* const* d_in, const int* in_sizes, int n_in,
                              void* d_out, int out_size, void* d_ws, size_t ws_size,
                              hipStream_t stream) {
    const float* logits = (const float*)d_in[0];
    const int*   labels = (const int*)d_in[1];
    float* out = (float*)d_out;
    u32*   ws  = (u32*)d_ws;
    long long n = (long long)in_sizes[0];

    rd_zero_ws<<<1, 512, 0, stream>>>(ws);
    rd_hist<<<BLOCKS, TPB, 0, stream>>>(logits, labels, ws, n);
    rd_finalize<<<1, 64, 0, stream>>>(ws, out);
}

// Round 10
// 273.168 us; speedup vs baseline: 1.0999x; 1.0999x over previous
//
#include <hip/hip_runtime.h>

typedef unsigned int u32;
typedef unsigned long long u64;

#define NB 10
#define BLOCKS 1024       // 4 blocks/CU, ONE generation (2048 blocks regresses: r4/r9)
#define TPB 256           // 4 waves
#define ITERS 32          // float4 batches per thread
#define DEPTH 8           // register ring depth: 16 outstanding 1KB loads/wave
#define WAVE_F4 (ITERS * 64)   // 2048 contiguous float4 per wave

// ws layout: bin b owns cache line at u32 index 32*b:
//   [32b+0..1] u64 sum(ffx), [32b+2] count, [32b+3] positives
__global__ void rd_zero_ws(u32* __restrict__ ws) {
    if (threadIdx.x < 320) ws[threadIdx.x] = 0u;
}

// Non-temporal 16 B loads via 4 scalar nt dword loads (clang merges adjacent
// nt loads into global_load_dwordx4 nt). Streamed data gets no L2 alloc —
// removing streaming pollution was the r7/r8 win (117 -> 97 -> <78 us).
__device__ __forceinline__ int4 nt_load_i4(const int4* p) {
    const int* q = (const int*)p;
    int4 r;
    r.x = __builtin_nontemporal_load(q);
    r.y = __builtin_nontemporal_load(q + 1);
    r.z = __builtin_nontemporal_load(q + 2);
    r.w = __builtin_nontemporal_load(q + 3);
    return r;
}

__device__ __forceinline__ float4 nt_load_f4(const float4* p) {
    const float* q = (const float*)p;
    float4 r;
    r.x = __builtin_nontemporal_load(q);
    r.y = __builtin_nontemporal_load(q + 1);
    r.z = __builtin_nontemporal_load(q + 2);
    r.w = __builtin_nontemporal_load(q + 3);
    return r;
}

// Per element: sigmoid -> bin -> 4 packed u64 register accumulators.
// 6-bit count/pos fields; 12-bit conf-frac fields (7-bit fixed point),
// unpack window 32 elems: 32*127 = 4064 < 4095 (field-safe).
__device__ __forceinline__ void rd_acc(float x, int lab,
                                       u64& c64, u64& p64, u64& flo, u64& fhi) {
    float e = __expf(-x);
    float conf = __builtin_amdgcn_rcpf(1.0f + e);        // sigmoid
    float t10 = __builtin_fmaf(conf, 10.0f, -1e-6f);     // bins are (l,u]
    int b = min(9, (int)t10);
    float frac = t10 - (float)b;                         // [0,1)
    u32 ffx = (u32)__builtin_fmaf(frac, 127.0f, 0.5f);   // 7-bit fixed point

    u32 sh6 = (u32)(b * 6);
    c64 += 1ull << sh6;                                  // 6-bit count fields
    p64 += ((u64)(u32)lab) << sh6;                       // 6-bit positive fields

    bool lo = b < 5;
    u32 sh12 = (u32)(b * 12);
    u32 shf = lo ? sh12 : (sh12 - 60u);
    u64 v = ((u64)ffx) << shf;                           // 12-bit fields, 5 per u64
    flo += lo ? v : 0ull;
    fhi += lo ? 0ull : v;
}

__device__ __forceinline__ void rd_acc4(const float4& x, const int4& y,
                                        u64& c64, u64& p64, u64& flo, u64& fhi) {
    rd_acc(x.x, y.x, c64, p64, flo, fhi);
    rd_acc(x.y, y.y, c64, p64, flo, fhi);
    rd_acc(x.z, y.z, c64, p64, flo, fhi);
    rd_acc(x.w, y.w, c64, p64, flo, fhi);
}

// r8 (full-nt, best: rd_hist < 78 us) with ONE change: DEPTH 4 -> 8.
// Same stream structure (1024 blocks, one generation, contiguous 32 KB
// per-wave walks); doubles per-wave outstanding loads (8 -> 16 x 1 KB)
// = ~256 KB/CU in flight. Fill kernels prove the fabric does 6.9 TB/s;
// r8 reads at ~3.6 TB/s effective — testing whether per-wave MLP binds.
__global__ __launch_bounds__(TPB, 4) void rd_hist(const float* __restrict__ logits,
                                                  const int* __restrict__ labels,
                                                  u32* __restrict__ ws,
                                                  long long n) {
    u32 cp[NB], cf[NB];
    #pragma unroll
    for (int b = 0; b < NB; ++b) { cp[b] = 0u; cf[b] = 0u; }

    const float4* l4 = (const float4*)logits;
    const int4*   i4 = (const int4*)labels;
    int lane = threadIdx.x & 63;
    int wave = threadIdx.x >> 6;
    long long nf4 = n >> 2;
    long long seg = (long long)blockIdx.x * (4 * WAVE_F4);

    u64 c64 = 0, p64 = 0, flo = 0, fhi = 0;

    #define UNPACK() do {                                                   \
        _Pragma("unroll")                                                   \
        for (int b = 0; b < NB; ++b) {                                      \
            u32 cnt = (u32)(c64 >> (6 * b)) & 63u;                          \
            u32 pos = (u32)(p64 >> (6 * b)) & 63u;                          \
            cp[b] += cnt | (pos << 16);                                     \
            cf[b] += (b < 5) ? ((u32)(flo >> (12 * b)) & 4095u)             \
                             : ((u32)(fhi >> (12 * (b - 5))) & 4095u);      \
        }                                                                   \
        c64 = 0; p64 = 0; flo = 0; fhi = 0;                                 \
    } while (0)

    if (seg + 4 * WAVE_F4 <= nf4) {
        long long gb = seg + (long long)wave * WAVE_F4;
        const float4* gl = l4 + gb + lane;
        const int4*   gi = i4 + gb + lane;

        // prologue: fill the ring (8 batches = 16 independent 16 B loads)
        float4 px0 = nt_load_f4(gl + 0 * 64);
        float4 px1 = nt_load_f4(gl + 1 * 64);
        float4 px2 = nt_load_f4(gl + 2 * 64);
        float4 px3 = nt_load_f4(gl + 3 * 64);
        float4 px4 = nt_load_f4(gl + 4 * 64);
        float4 px5 = nt_load_f4(gl + 5 * 64);
        float4 px6 = nt_load_f4(gl + 6 * 64);
        float4 px7 = nt_load_f4(gl + 7 * 64);
        int4 py0 = nt_load_i4(gi + 0 * 64);
        int4 py1 = nt_load_i4(gi + 1 * 64);
        int4 py2 = nt_load_i4(gi + 2 * 64);
        int4 py3 = nt_load_i4(gi + 3 * 64);
        int4 py4 = nt_load_i4(gi + 4 * 64);
        int4 py5 = nt_load_i4(gi + 5 * 64);
        int4 py6 = nt_load_i4(gi + 6 * 64);
        int4 py7 = nt_load_i4(gi + 7 * 64);

        #pragma unroll
        for (int t = 0; t < ITERS; ++t) {
            const int s = t & 7;            // static after unroll
            float4 x; int4 y;
            if      (s == 0) { x = px0; y = py0; }
            else if (s == 1) { x = px1; y = py1; }
            else if (s == 2) { x = px2; y = py2; }
            else if (s == 3) { x = px3; y = py3; }
            else if (s == 4) { x = px4; y = py4; }
            else if (s == 5) { x = px5; y = py5; }
            else if (s == 6) { x = px6; y = py6; }
            else             { x = px7; y = py7; }
            if (t + DEPTH < ITERS) {        // refill freed slot BEFORE compute
                const int r = (t + DEPTH) * 64;
                if      (s == 0) { px0 = nt_load_f4(gl + r); py0 = nt_load_i4(gi + r); }
                else if (s == 1) { px1 = nt_load_f4(gl + r); py1 = nt_load_i4(gi + r); }
                else if (s == 2) { px2 = nt_load_f4(gl + r); py2 = nt_load_i4(gi + r); }
                else if (s == 3) { px3 = nt_load_f4(gl + r); py3 = nt_load_i4(gi + r); }
                else if (s == 4) { px4 = nt_load_f4(gl + r); py4 = nt_load_i4(gi + r); }
                else if (s == 5) { px5 = nt_load_f4(gl + r); py5 = nt_load_i4(gi + r); }
                else if (s == 6) { px6 = nt_load_f4(gl + r); py6 = nt_load_i4(gi + r); }
                else             { px7 = nt_load_f4(gl + r); py7 = nt_load_i4(gi + r); }
            }
            rd_acc4(x, y, c64, p64, flo, fhi);
            if ((t & 7) == 7) UNPACK();     // every 32 elems, field-safe
        }
    }

    // generic tail (empty at N=2^25): direct atomics, rarely runs
    long long done_f4 = ((long long)gridDim.x < nf4 / (4 * WAVE_F4)
                             ? (long long)gridDim.x
                             : nf4 / (4 * WAVE_F4)) * (4 * WAVE_F4);
    long long tail = done_f4 * 4;
    if (tail < n) {
        long long tid    = (long long)blockIdx.x * blockDim.x + threadIdx.x;
        long long stride = (long long)gridDim.x * blockDim.x;
        for (long long i = tail + tid; i < n; i += stride) {
            float e = __expf(-logits[i]);
            float conf = __builtin_amdgcn_rcpf(1.0f + e);
            float t10 = __builtin_fmaf(conf, 10.0f, -1e-6f);
            int b = min(9, (int)t10);
            float frac = t10 - (float)b;
            u32 ffx = (u32)__builtin_fmaf(frac, 127.0f, 0.5f);
            atomicAdd((u64*)&ws[32 * b], (u64)ffx);
            atomicAdd(&ws[32 * b + 2], 1u);
            atomicAdd(&ws[32 * b + 3], (u32)labels[i]);
        }
    }
    #undef UNPACK

    // wave reduce + block combine (LDS: 320 B total)
    __shared__ u32 s_cp[4][NB];
    __shared__ u32 s_cf[4][NB];
    #pragma unroll
    for (int b = 0; b < NB; ++b) {
        u32 c = cp[b];                  // per-thread count <= 128 -> 16-bit safe
        u32 f = cf[b];
        #pragma unroll
        for (int off = 32; off; off >>= 1) {
            c += __shfl_down(c, off, 64);
            f += __shfl_down(f, off, 64);
        }
        if (lane == 0) { s_cp[wave][b] = c; s_cf[wave][b] = f; }
    }
    __syncthreads();

    if (threadIdx.x < NB) {
        int b = threadIdx.x;
        u32 c = s_cp[0][b] + s_cp[1][b] + s_cp[2][b] + s_cp[3][b];
        u64 f = (u64)s_cf[0][b] + s_cf[1][b] + s_cf[2][b] + s_cf[3][b];
        atomicAdd((u64*)&ws[32 * b], f);
        atomicAdd(&ws[32 * b + 2], c & 0xFFFFu);
        atomicAdd(&ws[32 * b + 3], c >> 16);
    }
}

__global__ void rd_finalize(const u32* __restrict__ ws, float* __restrict__ out) {
    int b = threadIdx.x;
    if (b < NB) {
        u64 f   = *(const u64*)&ws[32 * b];
        u32 cnt = ws[32 * b + 2];
        u32 pos = ws[32 * b + 3];
        double sumconf = ((double)b * (double)cnt + (double)f * (1.0 / 127.0)) * 0.1;
        float denom = fmaxf((float)cnt, 1.0f);
        bool ne = cnt > 0u;
        out[b]      = ne ? ((float)pos / denom) : 0.0f;
        out[NB + b] = ne ? (float)(sumconf / (double)denom) : 0.0f;
    }
}

extern "C" void kernel_launch(void* const* d_in, const int* in_sizes, int n_in,
                              void* d_out, int out_size, void* d_ws, size_t ws_size,
                              hipStream_t stream) {
    const float* logits = (const float*)d_in[0];
    const int*   labels = (const int*)d_in[1];
    float* out = (float*)d_out;
    u32*   ws  = (u32*)d_ws;
    long long n = (long long)in_sizes[0];

    rd_zero_ws<<<1, 512, 0, stream>>>(ws);
    rd_hist<<<BLOCKS, TPB, 0, stream>>>(logits, labels, ws, n);
    rd_finalize<<<1, 64, 0, stream>>>(ws, out);
}